// Round 8
// baseline (653.964 us; speedup 1.0000x reference)
//
#include <hip/hip_runtime.h>

typedef unsigned short u16;
typedef unsigned int   u32;
typedef __attribute__((ext_vector_type(4))) float f32x4;
typedef __attribute__((ext_vector_type(8))) short bf16x8;
typedef __attribute__((ext_vector_type(4))) unsigned short u16x4;

__device__ __forceinline__ u16 f2bf(float f) {
  u32 u = __float_as_uint(f);
  u = (u + 0x7FFFu + ((u >> 16) & 1u)) >> 16;
  return (u16)u;
}
__device__ __forceinline__ float bf2f(u16 h) {
  return __uint_as_float(((u32)h) << 16);
}

#define GLDS16(gptr, lptr)                                      \
  __builtin_amdgcn_global_load_lds(                             \
      (const __attribute__((address_space(1))) void*)(gptr),    \
      (__attribute__((address_space(3))) void*)(lptr), 16, 0, 0)

#define BARRIER                                                 \
  do {                                                          \
    asm volatile("" ::: "memory");                              \
    __builtin_amdgcn_s_barrier();                               \
    asm volatile("" ::: "memory");                              \
  } while (0)
#define WAITLGKM0 asm volatile("s_waitcnt lgkmcnt(0)" ::: "memory")
#define WAITVM2   asm volatile("s_waitcnt vmcnt(2)" ::: "memory")
#define WAITVM0   asm volatile("s_waitcnt vmcnt(0)" ::: "memory")
#define PRIO1 __builtin_amdgcn_s_setprio(1)
#define PRIO0 __builtin_amdgcn_s_setprio(0)

// ---------------- fused prep: w0T + weight cvts + tw0 pad + DOT zero ----------
#define PREP_TOTAL (6656 + 131072 + 32768 + 524288 + 1048576 + 32768)
__global__ __launch_bounds__(256) void prep(
    const float* __restrict__ bw0, const float* __restrict__ bw1,
    const float* __restrict__ bw2, const float* __restrict__ tw0,
    const float* __restrict__ tw1,
    float* __restrict__ w0T, u16* __restrict__ W1B, u16* __restrict__ W2B,
    u16* __restrict__ TW0B, u16* __restrict__ TW1B, float* __restrict__ DOT) {
  int i = blockIdx.x * 256 + threadIdx.x;
  if (i < 6656) {
    int k = i >> 9, n = i & 511;
    w0T[i] = bw0[n * 13 + k];
    return;
  }
  i -= 6656;
  if (i < 131072) { W1B[i] = f2bf(bw1[i]); return; }
  i -= 131072;
  if (i < 32768) { W2B[i] = f2bf(bw2[i]); return; }
  i -= 32768;
  if (i < 524288) {
    int r = i >> 9, k = i & 511;
    TW0B[i] = (k < 479) ? f2bf(tw0[r * 479 + k]) : (u16)0;
    return;
  }
  i -= 524288;
  if (i < 1048576) { TW1B[i] = f2bf(tw1[i]); return; }
  i -= 1048576;
  if (i < 32768) DOT[i] = 0.f;
}

// ---------------- bottom layer 0 (K=13), coalesced w0T ----------------
__global__ __launch_bounds__(256) void bot0(const float* __restrict__ dense,
                                            const float* __restrict__ w0T,
                                            const float* __restrict__ b0,
                                            u16* __restrict__ x1) {
  const int t = blockIdx.x * 256 + threadIdx.x;
  const int b = t >> 9, n = t & 511;
  const float* dr = dense + (size_t)b * 13;
  float s = b0[n];
#pragma unroll
  for (int k = 0; k < 13; ++k) s = fmaf(dr[k], w0T[k * 512 + n], s);
  x1[t] = f2bf(fmaxf(s, 0.f));
}

// ---------------- 128^2-tile bf16 GEMM (x2 only) ----------------
__global__ __launch_bounds__(256) void gemm_bt_relu(
    const u16* __restrict__ A, const u16* __restrict__ W,
    const float* __restrict__ bias, u16* __restrict__ C,
    int M, int N, int K) {
  __shared__ u16 Al[128 * 32];
  __shared__ u16 Bl[128 * 32];
  const int tid = threadIdx.x;
  const int wave = tid >> 6, lane = tid & 63;
  const int ntn = N >> 7;
  const int bm = blockIdx.x / ntn, bn = blockIdx.x % ntn;
  const int wm = (wave >> 1) << 6, wn = (wave & 1) << 6;
  const int fr = lane & 15, fq = lane >> 4;

  const int srow = wave * 16 + (lane >> 2);
  const int scol = (lane & 3) * 8;
  const u16* ag0 = A + (size_t)(bm * 128 + srow) * K + scol;
  const u16* ag1 = ag0 + (size_t)64 * K;
  const u16* wg0 = W + (size_t)(bn * 128 + srow) * K + scol;
  const u16* wg1 = wg0 + (size_t)64 * K;
  u16* la0 = &Al[(wave * 16) * 32];
  u16* la1 = &Al[(64 + wave * 16) * 32];
  u16* lb0 = &Bl[(wave * 16) * 32];
  u16* lb1 = &Bl[(64 + wave * 16) * 32];

  f32x4 acc[4][4] = {};

  for (int kt = 0; kt < K; kt += 32) {
    __syncthreads();
    GLDS16(ag0 + kt, la0);
    GLDS16(ag1 + kt, la1);
    GLDS16(wg0 + kt, lb0);
    GLDS16(wg1 + kt, lb1);
    __syncthreads();
    bf16x8 af[4], bfv[4];
#pragma unroll
    for (int i = 0; i < 4; ++i) {
      af[i]  = *(const bf16x8*)&Al[(wm + i * 16 + fr) * 32 + fq * 8];
      bfv[i] = *(const bf16x8*)&Bl[(wn + i * 16 + fr) * 32 + fq * 8];
    }
#pragma unroll
    for (int i = 0; i < 4; ++i)
#pragma unroll
      for (int j = 0; j < 4; ++j)
        acc[i][j] = __builtin_amdgcn_mfma_f32_16x16x32_bf16(af[i], bfv[j],
                                                            acc[i][j], 0, 0, 0);
  }

  const int crow0 = bm * 128 + wm, ccol0 = bn * 128 + wn;
#pragma unroll
  for (int i = 0; i < 4; ++i) {
#pragma unroll
    for (int j = 0; j < 4; ++j) {
      const int col = ccol0 + j * 16 + fr;
      const float bv = bias[col];
#pragma unroll
      for (int rr = 0; rr < 4; ++rr) {
        const int row = crow0 + i * 16 + fq * 4 + rr;
        float v = acc[i][j][rr] + bv;
        v = fmaxf(v, 0.f);
        C[(size_t)row * N + col] = f2bf(v);
      }
    }
  }
}

// ---------------- 256^2-tile, BK=64, 8-wave, 8-phase bf16 GEMM ----------------
#define LDA4(dst, FB, BUFE)                                                    \
  _Pragma("unroll") for (int f = 0; f < 4; ++f)                                \
  _Pragma("unroll") for (int ks = 0; ks < 2; ++ks)                             \
    dst[f][ks] = *(const bf16x8*)&lds[(BUFE) +                                 \
        (wm * 128 + (FB) * 16 + f * 16 + fr) * 64 +                            \
        ((ks * 4 + fq) ^ fr7) * 8];

#define LDB2(dst, GB, BUFE)                                                    \
  _Pragma("unroll") for (int g = 0; g < 2; ++g)                                \
  _Pragma("unroll") for (int ks = 0; ks < 2; ++ks)                             \
    dst[g][ks] = *(const bf16x8*)&lds[(BUFE) + 16384 +                         \
        (wn * 64 + (GB) * 16 + g * 16 + fr) * 64 +                             \
        ((ks * 4 + fq) ^ fr7) * 8];

#define MFQ(FB, GB, va, vb)                                                    \
  _Pragma("unroll") for (int f = 0; f < 4; ++f)                                \
  _Pragma("unroll") for (int g = 0; g < 2; ++g)                                \
  _Pragma("unroll") for (int ks = 0; ks < 2; ++ks)                             \
    acc[(FB) + f][(GB) + g] = __builtin_amdgcn_mfma_f32_16x16x32_bf16(         \
        va[f][ks], vb[g][ks], acc[(FB) + f][(GB) + g], 0, 0, 0);

template <int FUSE>
__global__ __launch_bounds__(512, 2) void gemm256(
    const u16* __restrict__ Ap, const u16* __restrict__ Wp,
    const float* __restrict__ bias, u16* __restrict__ C,
    const float* __restrict__ w2, float* __restrict__ dotacc,
    int N, int K) {
  __shared__ u16 lds[65536];  // 128 KiB
  const int tid = threadIdx.x;
  const int wave = tid >> 6, lane = tid & 63;
  const int wm = wave >> 2, wn = wave & 3;
  const int fr = lane & 15, fq = lane >> 4, fr7 = fr & 7;
  const int nkt = K >> 6, NP = nkt >> 1;

  const int nwg = gridDim.x;
  const int swz = (blockIdx.x & 7) * (nwg >> 3) + (blockIdx.x >> 3);
  const int ntn = N >> 8;
  const int bm = swz / ntn, bn = swz % ntn;

  auto stageH = [&](int tile, int half) {
    const int isB = half >> 1;
    const int h128 = half & 1;
    const u16* mat = isB ? Wp : Ap;
    const int brow0 = (isB ? bn : bm) * 256 + h128 * 128;
    u16* lb = lds + (tile & 1) * 32768 + isB * 16384 + h128 * 8192 + wave * 512;
    const int sl = lane >> 3;
    const int ch = (lane & 7) ^ sl;
    const u16* g = mat + (size_t)(brow0 + wave * 8 + sl) * K + tile * 64 + ch * 8;
    GLDS16(g, lb);
    GLDS16(g + (size_t)64 * K, lb + 4096);
  };

  f32x4 acc[8][4] = {};

  stageH(0, 0); stageH(0, 1); stageH(0, 2); stageH(0, 3);
  stageH(1, 0);
  WAITVM2;
  BARRIER;

  for (int p = 0; p < NP; ++p) {
    const int todd = 2 * p + 1, t2 = 2 * p + 2, t3 = 2 * p + 3;
    const bool last = (p == NP - 1);
    bf16x8 va[4][2], vb0[2][2], vb1[2][2];

    LDA4(va, 0, 0); LDB2(vb0, 0, 0);
    stageH(todd, 1);
    BARRIER; WAITLGKM0; PRIO1; MFQ(0, 0, va, vb0); PRIO0; BARRIER;
    LDB2(vb1, 2, 0);
    stageH(todd, 2);
    BARRIER; WAITLGKM0; PRIO1; MFQ(0, 2, va, vb1); PRIO0; BARRIER;
    LDA4(va, 4, 0);
    stageH(todd, 3);
    BARRIER; WAITLGKM0; PRIO1; MFQ(4, 0, va, vb0); PRIO0; BARRIER;
    if (t2 < nkt) stageH(t2, 0);
    BARRIER; PRIO1; MFQ(4, 2, va, vb1); PRIO0;
    if (last) { WAITVM0; } else { WAITVM2; }
    BARRIER;

    LDA4(va, 0, 32768); LDB2(vb0, 0, 32768);
    if (t2 < nkt) stageH(t2, 1);
    BARRIER; WAITLGKM0; PRIO1; MFQ(0, 0, va, vb0); PRIO0; BARRIER;
    LDB2(vb1, 2, 32768);
    if (t2 < nkt) stageH(t2, 2);
    BARRIER; WAITLGKM0; PRIO1; MFQ(0, 2, va, vb1); PRIO0; BARRIER;
    LDA4(va, 4, 32768);
    if (t2 < nkt) stageH(t2, 3);
    BARRIER; WAITLGKM0; PRIO1; MFQ(4, 0, va, vb0); PRIO0; BARRIER;
    if (t3 < nkt) stageH(t3, 0);
    BARRIER; PRIO1; MFQ(4, 2, va, vb1); PRIO0;
    if (!last) { WAITVM2; }
    BARRIER;
  }

  const int r0 = bm * 256 + wm * 128;
  const int c0 = bn * 256 + wn * 64;
  if (FUSE) {
    float bv[4], wv[4];
#pragma unroll
    for (int g = 0; g < 4; ++g) {
      const int col = c0 + g * 16 + fr;
      bv[g] = bias[col];
      wv[g] = w2[col];
    }
#pragma unroll
    for (int f = 0; f < 8; ++f) {
#pragma unroll
      for (int rr = 0; rr < 4; ++rr) {
        float s = 0.f;
#pragma unroll
        for (int g = 0; g < 4; ++g)
          s += fmaxf(acc[f][g][rr] + bv[g], 0.f) * wv[g];
#pragma unroll
        for (int off = 8; off >= 1; off >>= 1) s += __shfl_xor(s, off, 64);
        if (fr == 0)
          atomicAdd(&dotacc[r0 + f * 16 + fq * 4 + rr], s);
      }
    }
  } else {
#pragma unroll
    for (int g = 0; g < 4; ++g) {
      const int col = c0 + g * 16 + fr;
      const float bvv = bias[col];
#pragma unroll
      for (int f = 0; f < 8; ++f)
#pragma unroll
        for (int rr = 0; rr < 4; ++rr) {
          const int row = r0 + f * 16 + fq * 4 + rr;
          C[(size_t)row * N + col] = f2bf(fmaxf(acc[f][g][rr] + bvv, 0.f));
        }
    }
  }
}

// ---------------- fused x3 + embedding gather + interaction ----------------
// R4's interact with x3 computed in-kernel (VALU dots over x2/W2B, hidden
// under the random emb-load DRAM stall). Replaces the standalone x3 GEMM.
__global__ __launch_bounds__(256) void interact3(const float* __restrict__ emb,
                                                 const int* __restrict__ lsi,
                                                 const u16* __restrict__ x2,
                                                 const u16* __restrict__ W2B,
                                                 const float* __restrict__ b2v,
                                                 u16* __restrict__ R) {
  __shared__ u16 lds[4 * 32 * 128];  // 32 KiB
  const int tid = threadIdx.x;
  const int b0 = blockIdx.x * 4;

  // zero rows 27..31 of each sample
  {
    u32* lz = (u32*)lds;
#pragma unroll
    for (int z = 0; z < 5; ++z) {
      int i = z * 256 + tid;           // 0..1279
      int s = i / 320, o = i - s * 320;
      lz[s * 2048 + 1728 + o] = 0u;
    }
  }
  // emb rows first: issue the long-latency random loads (13 passes)
  {
    const int lane32 = tid & 31;
    const int item0 = tid >> 5;        // 0..7
#pragma unroll
    for (int p = 0; p < 13; ++p) {
      int w = p * 8 + item0;           // 0..103
      int s = w / 26, t = w - s * 26;
      int idx = lsi[t * 32768 + b0 + s];
      const float* er =
          emb + ((size_t)t * 100000 + (size_t)idx) * 128 + lane32 * 4;
      f32x4 u = *(const f32x4*)er;
      u16x4 q;
      q[0] = f2bf(u[0]); q[1] = f2bf(u[1]); q[2] = f2bf(u[2]); q[3] = f2bf(u[3]);
      int r = t + 1;
      int chunk = (lane32 >> 1) ^ (r & 7);
      *(u16x4*)&lds[(s * 32 + r) * 128 + chunk * 8 + (lane32 & 1) * 4] = q;
    }
  }
  // fused x3: thread computes 2 cols of one sample's x3 row (f32 FMA dots).
  // x2 row is L3-resident, W2B is 64KB L2-resident -> hidden under emb loads.
  {
    const int s = tid >> 6, c0 = (tid & 63) * 2;
    const u16* xr = x2 + (size_t)(b0 + s) * 256;
    const u16* wr0 = W2B + (size_t)c0 * 256;
    const u16* wr1 = wr0 + 256;
    float a0 = b2v[c0], a1 = b2v[c0 + 1];
#pragma unroll
    for (int k = 0; k < 256; k += 8) {
      bf16x8 xv  = *(const bf16x8*)&xr[k];
      bf16x8 wv0 = *(const bf16x8*)&wr0[k];
      bf16x8 wv1 = *(const bf16x8*)&wr1[k];
#pragma unroll
      for (int j = 0; j < 8; ++j) {
        const float xf = bf2f((u16)xv[j]);
        a0 = fmaf(xf, bf2f((u16)wv0[j]), a0);
        a1 = fmaf(xf, bf2f((u16)wv1[j]), a1);
      }
    }
    const u16 q0 = f2bf(fmaxf(a0, 0.f));
    const u16 q1 = f2bf(fmaxf(a1, 0.f));
    lds[(s * 32) * 128 + c0] = q0;       // row 0 (linear, swizzle r&7==0)
    lds[(s * 32) * 128 + c0 + 1] = q1;
    u16* Rb = R + (size_t)(b0 + s) * 512;
    Rb[c0] = q0;                          // R[:,0:128] = x3
    Rb[c0 + 1] = q1;
  }
  __syncthreads();

  const int wave = tid >> 6, lane = tid & 63;
  const int fr = lane & 15, fq = lane >> 4;
  const u16* ls = &lds[wave * 4096];
  u16* Rb = R + (size_t)(b0 + wave) * 512;

  if (lane < 33) Rb[479 + lane] = 0;     // zero K-pad cols 479..511

  bf16x8 tf[2][4];
#pragma unroll
  for (int mi = 0; mi < 2; ++mi) {
    const int r = mi * 16 + fr;
#pragma unroll
    for (int ks = 0; ks < 4; ++ks) {
      const int chunk = (ks * 4 + fq) ^ (r & 7);
      tf[mi][ks] = *(const bf16x8*)&ls[r * 128 + chunk * 8];
    }
  }

  f32x4 acc[2][2] = {};
#pragma unroll
  for (int ks = 0; ks < 4; ++ks)
#pragma unroll
    for (int mi = 0; mi < 2; ++mi)
#pragma unroll
      for (int ni = 0; ni < 2; ++ni)
        acc[mi][ni] = __builtin_amdgcn_mfma_f32_16x16x32_bf16(
            tf[mi][ks], tf[ni][ks], acc[mi][ni], 0, 0, 0);

#pragma unroll
  for (int mi = 0; mi < 2; ++mi)
#pragma unroll
    for (int ni = 0; ni < 2; ++ni)
#pragma unroll
      for (int rr = 0; rr < 4; ++rr) {
        const int i = mi * 16 + fq * 4 + rr;
        const int j = ni * 16 + fr;
        if (i < 27 && j < i)
          Rb[128 + (i * (i - 1)) / 2 + j] = f2bf(acc[mi][ni][rr]);
      }
}

// ---------------- sigmoid ----------------
__global__ __launch_bounds__(256) void sig_k(const float* __restrict__ accv,
                                             const float* __restrict__ b2,
                                             float* __restrict__ out, int n) {
  int i = blockIdx.x * 256 + threadIdx.x;
  if (i < n) out[i] = 1.f / (1.f + expf(-(accv[i] + b2[0])));
}

// ---------------- launch ----------------
extern "C" void kernel_launch(void* const* d_in, const int* in_sizes, int n_in,
                              void* d_out, int out_size, void* d_ws,
                              size_t ws_size, hipStream_t stream) {
  const float* dense = (const float*)d_in[0];
  const int*   lsi   = (const int*)d_in[1];
  const float* emb = (const float*)d_in[3];
  const float* bw0 = (const float*)d_in[4];
  const float* bb0 = (const float*)d_in[5];
  const float* bw1 = (const float*)d_in[6];
  const float* bb1 = (const float*)d_in[7];
  const float* bw2 = (const float*)d_in[8];
  const float* bb2 = (const float*)d_in[9];
  const float* tw0 = (const float*)d_in[10];
  const float* tb0 = (const float*)d_in[11];
  const float* tw1 = (const float*)d_in[12];
  const float* tb1 = (const float*)d_in[13];
  const float* tw2 = (const float*)d_in[14];
  const float* tb2 = (const float*)d_in[15];

  char* ws = (char*)d_ws;
  u16* W1B  = (u16*)ws; ws += (size_t)256 * 512 * 2;
  u16* W2B  = (u16*)ws; ws += (size_t)128 * 256 * 2;
  u16* TW0B = (u16*)ws; ws += (size_t)1024 * 512 * 2;
  u16* TW1B = (u16*)ws; ws += (size_t)1024 * 1024 * 2;
  float* DOT = (float*)ws; ws += (size_t)32768 * 4;
  float* W0T = (float*)ws; ws += (size_t)13 * 512 * 4;
  u16* SA   = (u16*)ws; ws += (size_t)32768 * 1024 * 2;  // x1 -> R
  u16* SB   = (u16*)ws; ws += (size_t)32768 * 1024 * 2;  // x2 -> z1

  prep<<<(PREP_TOTAL + 255) / 256, 256, 0, stream>>>(
      bw0, bw1, bw2, tw0, tw1, W0T, W1B, W2B, TW0B, TW1B, DOT);

  bot0<<<65536, 256, 0, stream>>>(dense, W0T, bb0, SA);                       // x1
  gemm_bt_relu<<<512, 256, 0, stream>>>(SA, W1B, bb1, SB, 32768, 256, 512);   // x2
  interact3<<<8192, 256, 0, stream>>>(emb, lsi, SB, W2B, bb2, SA);            // R (x3 fused)
  gemm256<0><<<512, 512, 0, stream>>>(SA, TW0B, tb0, SB, nullptr, nullptr,
                                      1024, 512);                             // z1
  gemm256<1><<<512, 512, 0, stream>>>(SB, TW1B, tb1, nullptr, tw2, DOT,
                                      1024, 1024);                            // z2.w2
  sig_k<<<128, 256, 0, stream>>>(DOT, tb2, (float*)d_out, 32768);
}

// Round 9
// 317.418 us; speedup vs baseline: 2.0603x; 2.0603x over previous
//
#include <hip/hip_runtime.h>

typedef unsigned short u16;
typedef unsigned int   u32;
typedef __attribute__((ext_vector_type(4))) float f32x4;
typedef __attribute__((ext_vector_type(8))) short bf16x8;
typedef __attribute__((ext_vector_type(4))) unsigned short u16x4;

__device__ __forceinline__ u16 f2bf(float f) {
  u32 u = __float_as_uint(f);
  u = (u + 0x7FFFu + ((u >> 16) & 1u)) >> 16;
  return (u16)u;
}
__device__ __forceinline__ float bf2f(u16 h) {
  return __uint_as_float(((u32)h) << 16);
}

#define GLDS16(gptr, lptr)                                      \
  __builtin_amdgcn_global_load_lds(                             \
      (const __attribute__((address_space(1))) void*)(gptr),    \
      (__attribute__((address_space(3))) void*)(lptr), 16, 0, 0)

#define BARRIER                                                 \
  do {                                                          \
    asm volatile("" ::: "memory");                              \
    __builtin_amdgcn_s_barrier();                               \
    asm volatile("" ::: "memory");                              \
  } while (0)
#define WAITLGKM0 asm volatile("s_waitcnt lgkmcnt(0)" ::: "memory")
#define WAITVM2   asm volatile("s_waitcnt vmcnt(2)" ::: "memory")
#define WAITVM0   asm volatile("s_waitcnt vmcnt(0)" ::: "memory")
#define PRIO1 __builtin_amdgcn_s_setprio(1)
#define PRIO0 __builtin_amdgcn_s_setprio(0)

// ---------------- fused prep: w0T + weight cvts + tw0 pad + DOT zero ----------
#define PREP_TOTAL (6656 + 131072 + 32768 + 524288 + 1048576 + 32768)
__global__ __launch_bounds__(256) void prep(
    const float* __restrict__ bw0, const float* __restrict__ bw1,
    const float* __restrict__ bw2, const float* __restrict__ tw0,
    const float* __restrict__ tw1,
    float* __restrict__ w0T, u16* __restrict__ W1B, u16* __restrict__ W2B,
    u16* __restrict__ TW0B, u16* __restrict__ TW1B, float* __restrict__ DOT) {
  int i = blockIdx.x * 256 + threadIdx.x;
  if (i < 6656) {
    int k = i >> 9, n = i & 511;
    w0T[i] = bw0[n * 13 + k];
    return;
  }
  i -= 6656;
  if (i < 131072) { W1B[i] = f2bf(bw1[i]); return; }
  i -= 131072;
  if (i < 32768) { W2B[i] = f2bf(bw2[i]); return; }
  i -= 32768;
  if (i < 524288) {
    int r = i >> 9, k = i & 511;
    TW0B[i] = (k < 479) ? f2bf(tw0[r * 479 + k]) : (u16)0;
    return;
  }
  i -= 524288;
  if (i < 1048576) { TW1B[i] = f2bf(tw1[i]); return; }
  i -= 1048576;
  if (i < 32768) DOT[i] = 0.f;
}

// ---------------- bottom layer 0 (K=13), coalesced w0T ----------------
__global__ __launch_bounds__(256) void bot0(const float* __restrict__ dense,
                                            const float* __restrict__ w0T,
                                            const float* __restrict__ b0,
                                            u16* __restrict__ x1) {
  const int t = blockIdx.x * 256 + threadIdx.x;
  const int b = t >> 9, n = t & 511;
  const float* dr = dense + (size_t)b * 13;
  float s = b0[n];
#pragma unroll
  for (int k = 0; k < 13; ++k) s = fmaf(dr[k], w0T[k * 512 + n], s);
  x1[t] = f2bf(fmaxf(s, 0.f));
}

// ---------------- 128^2-tile bf16 GEMM (x2 / x3) ----------------
__global__ __launch_bounds__(256) void gemm_bt_relu(
    const u16* __restrict__ A, const u16* __restrict__ W,
    const float* __restrict__ bias, u16* __restrict__ C,
    int M, int N, int K) {
  __shared__ u16 Al[128 * 32];
  __shared__ u16 Bl[128 * 32];
  const int tid = threadIdx.x;
  const int wave = tid >> 6, lane = tid & 63;
  const int ntn = N >> 7;
  const int bm = blockIdx.x / ntn, bn = blockIdx.x % ntn;
  const int wm = (wave >> 1) << 6, wn = (wave & 1) << 6;
  const int fr = lane & 15, fq = lane >> 4;

  const int srow = wave * 16 + (lane >> 2);
  const int scol = (lane & 3) * 8;
  const u16* ag0 = A + (size_t)(bm * 128 + srow) * K + scol;
  const u16* ag1 = ag0 + (size_t)64 * K;
  const u16* wg0 = W + (size_t)(bn * 128 + srow) * K + scol;
  const u16* wg1 = wg0 + (size_t)64 * K;
  u16* la0 = &Al[(wave * 16) * 32];
  u16* la1 = &Al[(64 + wave * 16) * 32];
  u16* lb0 = &Bl[(wave * 16) * 32];
  u16* lb1 = &Bl[(64 + wave * 16) * 32];

  f32x4 acc[4][4] = {};

  for (int kt = 0; kt < K; kt += 32) {
    __syncthreads();
    GLDS16(ag0 + kt, la0);
    GLDS16(ag1 + kt, la1);
    GLDS16(wg0 + kt, lb0);
    GLDS16(wg1 + kt, lb1);
    __syncthreads();
    bf16x8 af[4], bfv[4];
#pragma unroll
    for (int i = 0; i < 4; ++i) {
      af[i]  = *(const bf16x8*)&Al[(wm + i * 16 + fr) * 32 + fq * 8];
      bfv[i] = *(const bf16x8*)&Bl[(wn + i * 16 + fr) * 32 + fq * 8];
    }
#pragma unroll
    for (int i = 0; i < 4; ++i)
#pragma unroll
      for (int j = 0; j < 4; ++j)
        acc[i][j] = __builtin_amdgcn_mfma_f32_16x16x32_bf16(af[i], bfv[j],
                                                            acc[i][j], 0, 0, 0);
  }

  const int crow0 = bm * 128 + wm, ccol0 = bn * 128 + wn;
#pragma unroll
  for (int i = 0; i < 4; ++i) {
#pragma unroll
    for (int j = 0; j < 4; ++j) {
      const int col = ccol0 + j * 16 + fr;
      const float bv = bias[col];
#pragma unroll
      for (int rr = 0; rr < 4; ++rr) {
        const int row = crow0 + i * 16 + fq * 4 + rr;
        float v = acc[i][j][rr] + bv;
        v = fmaxf(v, 0.f);
        C[(size_t)row * N + col] = f2bf(v);
      }
    }
  }
}

// ---------------- 256^2-tile, BK=64, 8-wave, 8-phase bf16 GEMM ----------------
#define LDA4(dst, FB, BUFE)                                                    \
  _Pragma("unroll") for (int f = 0; f < 4; ++f)                                \
  _Pragma("unroll") for (int ks = 0; ks < 2; ++ks)                             \
    dst[f][ks] = *(const bf16x8*)&lds[(BUFE) +                                 \
        (wm * 128 + (FB) * 16 + f * 16 + fr) * 64 +                            \
        ((ks * 4 + fq) ^ fr7) * 8];

#define LDB2(dst, GB, BUFE)                                                    \
  _Pragma("unroll") for (int g = 0; g < 2; ++g)                                \
  _Pragma("unroll") for (int ks = 0; ks < 2; ++ks)                             \
    dst[g][ks] = *(const bf16x8*)&lds[(BUFE) + 16384 +                         \
        (wn * 64 + (GB) * 16 + g * 16 + fr) * 64 +                             \
        ((ks * 4 + fq) ^ fr7) * 8];

#define MFQ(FB, GB, va, vb)                                                    \
  _Pragma("unroll") for (int f = 0; f < 4; ++f)                                \
  _Pragma("unroll") for (int g = 0; g < 2; ++g)                                \
  _Pragma("unroll") for (int ks = 0; ks < 2; ++ks)                             \
    acc[(FB) + f][(GB) + g] = __builtin_amdgcn_mfma_f32_16x16x32_bf16(         \
        va[f][ks], vb[g][ks], acc[(FB) + f][(GB) + g], 0, 0, 0);

template <int FUSE>
__global__ __launch_bounds__(512, 2) void gemm256(
    const u16* __restrict__ Ap, const u16* __restrict__ Wp,
    const float* __restrict__ bias, u16* __restrict__ C,
    const float* __restrict__ w2, float* __restrict__ dotacc,
    int N, int K) {
  __shared__ u16 lds[65536];  // 128 KiB
  const int tid = threadIdx.x;
  const int wave = tid >> 6, lane = tid & 63;
  const int wm = wave >> 2, wn = wave & 3;
  const int fr = lane & 15, fq = lane >> 4, fr7 = fr & 7;
  const int nkt = K >> 6, NP = nkt >> 1;

  const int nwg = gridDim.x;
  const int swz = (blockIdx.x & 7) * (nwg >> 3) + (blockIdx.x >> 3);
  const int ntn = N >> 8;
  const int bm = swz / ntn, bn = swz % ntn;

  auto stageH = [&](int tile, int half) {
    const int isB = half >> 1;
    const int h128 = half & 1;
    const u16* mat = isB ? Wp : Ap;
    const int brow0 = (isB ? bn : bm) * 256 + h128 * 128;
    u16* lb = lds + (tile & 1) * 32768 + isB * 16384 + h128 * 8192 + wave * 512;
    const int sl = lane >> 3;
    const int ch = (lane & 7) ^ sl;
    const u16* g = mat + (size_t)(brow0 + wave * 8 + sl) * K + tile * 64 + ch * 8;
    GLDS16(g, lb);
    GLDS16(g + (size_t)64 * K, lb + 4096);
  };

  f32x4 acc[8][4] = {};

  stageH(0, 0); stageH(0, 1); stageH(0, 2); stageH(0, 3);
  stageH(1, 0);
  WAITVM2;
  BARRIER;

  for (int p = 0; p < NP; ++p) {
    const int todd = 2 * p + 1, t2 = 2 * p + 2, t3 = 2 * p + 3;
    const bool last = (p == NP - 1);
    bf16x8 va[4][2], vb0[2][2], vb1[2][2];

    LDA4(va, 0, 0); LDB2(vb0, 0, 0);
    stageH(todd, 1);
    BARRIER; WAITLGKM0; PRIO1; MFQ(0, 0, va, vb0); PRIO0; BARRIER;
    LDB2(vb1, 2, 0);
    stageH(todd, 2);
    BARRIER; WAITLGKM0; PRIO1; MFQ(0, 2, va, vb1); PRIO0; BARRIER;
    LDA4(va, 4, 0);
    stageH(todd, 3);
    BARRIER; WAITLGKM0; PRIO1; MFQ(4, 0, va, vb0); PRIO0; BARRIER;
    if (t2 < nkt) stageH(t2, 0);
    BARRIER; PRIO1; MFQ(4, 2, va, vb1); PRIO0;
    if (last) { WAITVM0; } else { WAITVM2; }
    BARRIER;

    LDA4(va, 0, 32768); LDB2(vb0, 0, 32768);
    if (t2 < nkt) stageH(t2, 1);
    BARRIER; WAITLGKM0; PRIO1; MFQ(0, 0, va, vb0); PRIO0; BARRIER;
    LDB2(vb1, 2, 32768);
    if (t2 < nkt) stageH(t2, 2);
    BARRIER; WAITLGKM0; PRIO1; MFQ(0, 2, va, vb1); PRIO0; BARRIER;
    LDA4(va, 4, 32768);
    if (t2 < nkt) stageH(t2, 3);
    BARRIER; WAITLGKM0; PRIO1; MFQ(4, 0, va, vb0); PRIO0; BARRIER;
    if (t3 < nkt) stageH(t3, 0);
    BARRIER; PRIO1; MFQ(4, 2, va, vb1); PRIO0;
    if (!last) { WAITVM2; }
    BARRIER;
  }

  const int r0 = bm * 256 + wm * 128;
  const int c0 = bn * 256 + wn * 64;
  if (FUSE) {
    float bv[4], wv[4];
#pragma unroll
    for (int g = 0; g < 4; ++g) {
      const int col = c0 + g * 16 + fr;
      bv[g] = bias[col];
      wv[g] = w2[col];
    }
#pragma unroll
    for (int f = 0; f < 8; ++f) {
#pragma unroll
      for (int rr = 0; rr < 4; ++rr) {
        float s = 0.f;
#pragma unroll
        for (int g = 0; g < 4; ++g)
          s += fmaxf(acc[f][g][rr] + bv[g], 0.f) * wv[g];
#pragma unroll
        for (int off = 8; off >= 1; off >>= 1) s += __shfl_xor(s, off, 64);
        if (fr == 0)
          atomicAdd(&dotacc[r0 + f * 16 + fq * 4 + rr], s);
      }
    }
  } else {
#pragma unroll
    for (int g = 0; g < 4; ++g) {
      const int col = c0 + g * 16 + fr;
      const float bvv = bias[col];
#pragma unroll
      for (int f = 0; f < 8; ++f)
#pragma unroll
        for (int rr = 0; rr < 4; ++rr) {
          const int row = r0 + f * 16 + fq * 4 + rr;
          C[(size_t)row * N + col] = f2bf(fmaxf(acc[f][g][rr] + bvv, 0.f));
        }
    }
  }
}

// ---------------- fused embedding gather + interaction (occupancy v3) --------
// 2 samples/block, 16 KiB LDS, <=64 VGPR forced -> 8 blocks/CU = 32 waves/CU
// (vs 20 for the 4-sample version). Gram split: 2 waves per sample (mi=wave&1).
__global__ __launch_bounds__(256, 8) void interactO(
    const float* __restrict__ emb, const int* __restrict__ lsi,
    const u16* __restrict__ x3, u16* __restrict__ R) {
  __shared__ u16 lds[2 * 32 * 128];  // 16 KiB
  const int tid = threadIdx.x;
  const int b0 = blockIdx.x * 2;

  // zero rows 27..31 of both samples (2 x 320 u32)
  {
    u32* lz = (u32*)lds;
#pragma unroll
    for (int z = 0; z < 3; ++z) {
      int i = z * 256 + tid;           // 0..767, need 0..639
      if (i < 640) {
        int s = (i >= 320) ? 1 : 0, o = i - s * 320;
        lz[s * 2048 + 1728 + o] = 0u;
      }
    }
  }
  // x3 -> row 0 (linear: row&7==0)
  if (tid < 32) {
    int s = tid >> 4, l = tid & 15;
    *(bf16x8*)&lds[s * 4096 + l * 8] =
        *(const bf16x8*)&x3[(size_t)(b0 + s) * 128 + l * 8];
  }
  // emb rows: 52 items, 32 lanes/item, 7 passes (guarded)
  {
    const int lane32 = tid & 31;
    const int item0 = tid >> 5;        // 0..7
#pragma unroll
    for (int p = 0; p < 7; ++p) {
      int w = p * 8 + item0;           // 0..55
      if (w < 52) {
        int s = (w >= 26) ? 1 : 0, t = w - s * 26;
        int idx = lsi[t * 32768 + b0 + s];
        const float* er =
            emb + ((size_t)t * 100000 + (size_t)idx) * 128 + lane32 * 4;
        f32x4 u = *(const f32x4*)er;
        u16x4 q;
        q[0] = f2bf(u[0]); q[1] = f2bf(u[1]); q[2] = f2bf(u[2]); q[3] = f2bf(u[3]);
        int r = t + 1;
        int chunk = (lane32 >> 1) ^ (r & 7);
        *(u16x4*)&lds[(s * 32 + r) * 128 + chunk * 8 + (lane32 & 1) * 4] = q;
      }
    }
  }
  __syncthreads();

  const int wave = tid >> 6, lane = tid & 63;
  const int s = wave >> 1, mi = wave & 1;
  const int fr = lane & 15, fq = lane >> 4;
  const u16* ls = &lds[s * 4096];
  u16* Rb = R + (size_t)(b0 + s) * 512;

  if (mi == 0) {
    *(u32*)&Rb[lane * 2] = *(const u32*)&ls[lane * 2];  // R[:,0:128] = x3
    if (lane < 33) Rb[479 + lane] = 0;                  // zero K-pad
  }

  // fragments for both row-halves (B-operand needs both; A picks by mi)
  bf16x8 tf0[4], tf1[4];
#pragma unroll
  for (int ks = 0; ks < 4; ++ks) {
    const int r0 = fr, r1 = 16 + fr;
    tf0[ks] = *(const bf16x8*)&ls[r0 * 128 + (((ks * 4 + fq) ^ (r0 & 7)) * 8)];
    tf1[ks] = *(const bf16x8*)&ls[r1 * 128 + (((ks * 4 + fq) ^ (r1 & 7)) * 8)];
  }

  f32x4 acc[2] = {};
  if (mi == 0) {
#pragma unroll
    for (int ks = 0; ks < 4; ++ks) {
      acc[0] = __builtin_amdgcn_mfma_f32_16x16x32_bf16(tf0[ks], tf0[ks],
                                                       acc[0], 0, 0, 0);
      acc[1] = __builtin_amdgcn_mfma_f32_16x16x32_bf16(tf0[ks], tf1[ks],
                                                       acc[1], 0, 0, 0);
    }
  } else {
#pragma unroll
    for (int ks = 0; ks < 4; ++ks) {
      acc[0] = __builtin_amdgcn_mfma_f32_16x16x32_bf16(tf1[ks], tf0[ks],
                                                       acc[0], 0, 0, 0);
      acc[1] = __builtin_amdgcn_mfma_f32_16x16x32_bf16(tf1[ks], tf1[ks],
                                                       acc[1], 0, 0, 0);
    }
  }

#pragma unroll
  for (int ni = 0; ni < 2; ++ni)
#pragma unroll
    for (int rr = 0; rr < 4; ++rr) {
      const int i = mi * 16 + fq * 4 + rr;
      const int j = ni * 16 + fr;
      if (i < 27 && j < i)
        Rb[128 + (i * (i - 1)) / 2 + j] = f2bf(acc[ni][rr]);
    }
}

// ---------------- sigmoid ----------------
__global__ __launch_bounds__(256) void sig_k(const float* __restrict__ accv,
                                             const float* __restrict__ b2,
                                             float* __restrict__ out, int n) {
  int i = blockIdx.x * 256 + threadIdx.x;
  if (i < n) out[i] = 1.f / (1.f + expf(-(accv[i] + b2[0])));
}

// ---------------- launch ----------------
extern "C" void kernel_launch(void* const* d_in, const int* in_sizes, int n_in,
                              void* d_out, int out_size, void* d_ws,
                              size_t ws_size, hipStream_t stream) {
  const float* dense = (const float*)d_in[0];
  const int*   lsi   = (const int*)d_in[1];
  const float* emb = (const float*)d_in[3];
  const float* bw0 = (const float*)d_in[4];
  const float* bb0 = (const float*)d_in[5];
  const float* bw1 = (const float*)d_in[6];
  const float* bb1 = (const float*)d_in[7];
  const float* bw2 = (const float*)d_in[8];
  const float* bb2 = (const float*)d_in[9];
  const float* tw0 = (const float*)d_in[10];
  const float* tb0 = (const float*)d_in[11];
  const float* tw1 = (const float*)d_in[12];
  const float* tb1 = (const float*)d_in[13];
  const float* tw2 = (const float*)d_in[14];
  const float* tb2 = (const float*)d_in[15];

  char* ws = (char*)d_ws;
  u16* W1B  = (u16*)ws; ws += (size_t)256 * 512 * 2;
  u16* W2B  = (u16*)ws; ws += (size_t)128 * 256 * 2;
  u16* TW0B = (u16*)ws; ws += (size_t)1024 * 512 * 2;
  u16* TW1B = (u16*)ws; ws += (size_t)1024 * 1024 * 2;
  float* DOT = (float*)ws; ws += (size_t)32768 * 4;
  float* W0T = (float*)ws; ws += (size_t)13 * 512 * 4;
  u16* X3   = (u16*)ws; ws += (size_t)32768 * 128 * 2;
  u16* SA   = (u16*)ws; ws += (size_t)32768 * 1024 * 2;  // x1 -> R
  u16* SB   = (u16*)ws; ws += (size_t)32768 * 1024 * 2;  // x2 -> z1

  prep<<<(PREP_TOTAL + 255) / 256, 256, 0, stream>>>(
      bw0, bw1, bw2, tw0, tw1, W0T, W1B, W2B, TW0B, TW1B, DOT);

  bot0<<<65536, 256, 0, stream>>>(dense, W0T, bb0, SA);                       // x1
  gemm_bt_relu<<<512, 256, 0, stream>>>(SA, W1B, bb1, SB, 32768, 256, 512);   // x2
  gemm_bt_relu<<<256, 256, 0, stream>>>(SB, W2B, bb2, X3, 32768, 128, 256);   // x3
  interactO<<<16384, 256, 0, stream>>>(emb, lsi, X3, SA);                     // R
  gemm256<0><<<512, 512, 0, stream>>>(SA, TW0B, tb0, SB, nullptr, nullptr,
                                      1024, 512);                             // z1
  gemm256<1><<<512, 512, 0, stream>>>(SB, TW1B, tb1, nullptr, tw2, DOT,
                                      1024, 1024);                            // z2.w2
  sig_k<<<128, 256, 0, stream>>>(DOT, tb2, (float*)d_out, 32768);
}

// Round 10
// 311.825 us; speedup vs baseline: 2.0972x; 1.0179x over previous
//
#include <hip/hip_runtime.h>

typedef unsigned short u16;
typedef unsigned int   u32;
typedef __attribute__((ext_vector_type(4))) float f32x4;
typedef __attribute__((ext_vector_type(8))) short bf16x8;
typedef __attribute__((ext_vector_type(4))) unsigned short u16x4;

__device__ __forceinline__ u16 f2bf(float f) {
  u32 u = __float_as_uint(f);
  u = (u + 0x7FFFu + ((u >> 16) & 1u)) >> 16;
  return (u16)u;
}
__device__ __forceinline__ float bf2f(u16 h) {
  return __uint_as_float(((u32)h) << 16);
}

#define GLDS16(gptr, lptr)                                      \
  __builtin_amdgcn_global_load_lds(                             \
      (const __attribute__((address_space(1))) void*)(gptr),    \
      (__attribute__((address_space(3))) void*)(lptr), 16, 0, 0)

#define BARRIER                                                 \
  do {                                                          \
    asm volatile("" ::: "memory");                              \
    __builtin_amdgcn_s_barrier();                               \
    asm volatile("" ::: "memory");                              \
  } while (0)
#define WAITLGKM0 asm volatile("s_waitcnt lgkmcnt(0)" ::: "memory")
#define WAITVM2   asm volatile("s_waitcnt vmcnt(2)" ::: "memory")
#define WAITVM0   asm volatile("s_waitcnt vmcnt(0)" ::: "memory")
#define PRIO1 __builtin_amdgcn_s_setprio(1)
#define PRIO0 __builtin_amdgcn_s_setprio(0)

// ---------------- fused prep: w0T + weight cvts + tw0 pad + DOT zero ----------
#define PREP_TOTAL (6656 + 131072 + 32768 + 524288 + 1048576 + 32768)
__global__ __launch_bounds__(256) void prep(
    const float* __restrict__ bw0, const float* __restrict__ bw1,
    const float* __restrict__ bw2, const float* __restrict__ tw0,
    const float* __restrict__ tw1,
    float* __restrict__ w0T, u16* __restrict__ W1B, u16* __restrict__ W2B,
    u16* __restrict__ TW0B, u16* __restrict__ TW1B, float* __restrict__ DOT) {
  int i = blockIdx.x * 256 + threadIdx.x;
  if (i < 6656) {
    int k = i >> 9, n = i & 511;
    w0T[i] = bw0[n * 13 + k];
    return;
  }
  i -= 6656;
  if (i < 131072) { W1B[i] = f2bf(bw1[i]); return; }
  i -= 131072;
  if (i < 32768) { W2B[i] = f2bf(bw2[i]); return; }
  i -= 32768;
  if (i < 524288) {
    int r = i >> 9, k = i & 511;
    TW0B[i] = (k < 479) ? f2bf(tw0[r * 479 + k]) : (u16)0;
    return;
  }
  i -= 524288;
  if (i < 1048576) { TW1B[i] = f2bf(tw1[i]); return; }
  i -= 1048576;
  if (i < 32768) DOT[i] = 0.f;
}

// ---------------- bottom layer 0 (K=13), coalesced w0T, grid-stride ----------
__global__ __launch_bounds__(256) void bot0(const float* __restrict__ dense,
                                            const float* __restrict__ w0T,
                                            const float* __restrict__ b0,
                                            u16* __restrict__ x1) {
  for (int t = blockIdx.x * 256 + threadIdx.x; t < 32768 * 512;
       t += gridDim.x * 256) {
    const int b = t >> 9, n = t & 511;
    const float* dr = dense + (size_t)b * 13;
    float s = b0[n];
#pragma unroll
    for (int k = 0; k < 13; ++k) s = fmaf(dr[k], w0T[k * 512 + n], s);
    x1[t] = f2bf(fmaxf(s, 0.f));
  }
}

// ---------------- 128^2-tile bf16 GEMM (x2 / x3) ----------------
__global__ __launch_bounds__(256) void gemm_bt_relu(
    const u16* __restrict__ A, const u16* __restrict__ W,
    const float* __restrict__ bias, u16* __restrict__ C,
    int M, int N, int K) {
  __shared__ u16 Al[128 * 32];
  __shared__ u16 Bl[128 * 32];
  const int tid = threadIdx.x;
  const int wave = tid >> 6, lane = tid & 63;
  const int ntn = N >> 7;
  const int bm = blockIdx.x / ntn, bn = blockIdx.x % ntn;
  const int wm = (wave >> 1) << 6, wn = (wave & 1) << 6;
  const int fr = lane & 15, fq = lane >> 4;

  const int srow = wave * 16 + (lane >> 2);
  const int scol = (lane & 3) * 8;
  const u16* ag0 = A + (size_t)(bm * 128 + srow) * K + scol;
  const u16* ag1 = ag0 + (size_t)64 * K;
  const u16* wg0 = W + (size_t)(bn * 128 + srow) * K + scol;
  const u16* wg1 = wg0 + (size_t)64 * K;
  u16* la0 = &Al[(wave * 16) * 32];
  u16* la1 = &Al[(64 + wave * 16) * 32];
  u16* lb0 = &Bl[(wave * 16) * 32];
  u16* lb1 = &Bl[(64 + wave * 16) * 32];

  f32x4 acc[4][4] = {};

  for (int kt = 0; kt < K; kt += 32) {
    __syncthreads();
    GLDS16(ag0 + kt, la0);
    GLDS16(ag1 + kt, la1);
    GLDS16(wg0 + kt, lb0);
    GLDS16(wg1 + kt, lb1);
    __syncthreads();
    bf16x8 af[4], bfv[4];
#pragma unroll
    for (int i = 0; i < 4; ++i) {
      af[i]  = *(const bf16x8*)&Al[(wm + i * 16 + fr) * 32 + fq * 8];
      bfv[i] = *(const bf16x8*)&Bl[(wn + i * 16 + fr) * 32 + fq * 8];
    }
#pragma unroll
    for (int i = 0; i < 4; ++i)
#pragma unroll
      for (int j = 0; j < 4; ++j)
        acc[i][j] = __builtin_amdgcn_mfma_f32_16x16x32_bf16(af[i], bfv[j],
                                                            acc[i][j], 0, 0, 0);
  }

  const int crow0 = bm * 128 + wm, ccol0 = bn * 128 + wn;
#pragma unroll
  for (int i = 0; i < 4; ++i) {
#pragma unroll
    for (int j = 0; j < 4; ++j) {
      const int col = ccol0 + j * 16 + fr;
      const float bv = bias[col];
#pragma unroll
      for (int rr = 0; rr < 4; ++rr) {
        const int row = crow0 + i * 16 + fq * 4 + rr;
        float v = acc[i][j][rr] + bv;
        v = fmaxf(v, 0.f);
        C[(size_t)row * N + col] = f2bf(v);
      }
    }
  }
}

// ---------------- 256^2-tile, BK=64, 8-wave, 8-phase bf16 GEMM ----------------
#define LDA4(dst, FB, BUFE)                                                    \
  _Pragma("unroll") for (int f = 0; f < 4; ++f)                                \
  _Pragma("unroll") for (int ks = 0; ks < 2; ++ks)                             \
    dst[f][ks] = *(const bf16x8*)&lds[(BUFE) +                                 \
        (wm * 128 + (FB) * 16 + f * 16 + fr) * 64 +                            \
        ((ks * 4 + fq) ^ fr7) * 8];

#define LDB2(dst, GB, BUFE)                                                    \
  _Pragma("unroll") for (int g = 0; g < 2; ++g)                                \
  _Pragma("unroll") for (int ks = 0; ks < 2; ++ks)                             \
    dst[g][ks] = *(const bf16x8*)&lds[(BUFE) + 16384 +                         \
        (wn * 64 + (GB) * 16 + g * 16 + fr) * 64 +                             \
        ((ks * 4 + fq) ^ fr7) * 8];

#define MFQ(FB, GB, va, vb)                                                    \
  _Pragma("unroll") for (int f = 0; f < 4; ++f)                                \
  _Pragma("unroll") for (int g = 0; g < 2; ++g)                                \
  _Pragma("unroll") for (int ks = 0; ks < 2; ++ks)                             \
    acc[(FB) + f][(GB) + g] = __builtin_amdgcn_mfma_f32_16x16x32_bf16(         \
        va[f][ks], vb[g][ks], acc[(FB) + f][(GB) + g], 0, 0, 0);

template <int FUSE>
__global__ __launch_bounds__(512, 2) void gemm256(
    const u16* __restrict__ Ap, const u16* __restrict__ Wp,
    const float* __restrict__ bias, u16* __restrict__ C,
    const float* __restrict__ w2, float* __restrict__ dotacc,
    int N, int K) {
  __shared__ u16 lds[65536];  // 128 KiB
  const int tid = threadIdx.x;
  const int wave = tid >> 6, lane = tid & 63;
  const int wm = wave >> 2, wn = wave & 3;
  const int fr = lane & 15, fq = lane >> 4, fr7 = fr & 7;
  const int nkt = K >> 6, NP = nkt >> 1;

  const int nwg = gridDim.x;
  const int swz = (blockIdx.x & 7) * (nwg >> 3) + (blockIdx.x >> 3);
  const int ntn = N >> 8;
  const int bm = swz / ntn, bn = swz % ntn;

  auto stageH = [&](int tile, int half) {
    const int isB = half >> 1;
    const int h128 = half & 1;
    const u16* mat = isB ? Wp : Ap;
    const int brow0 = (isB ? bn : bm) * 256 + h128 * 128;
    u16* lb = lds + (tile & 1) * 32768 + isB * 16384 + h128 * 8192 + wave * 512;
    const int sl = lane >> 3;
    const int ch = (lane & 7) ^ sl;
    const u16* g = mat + (size_t)(brow0 + wave * 8 + sl) * K + tile * 64 + ch * 8;
    GLDS16(g, lb);
    GLDS16(g + (size_t)64 * K, lb + 4096);
  };

  f32x4 acc[8][4] = {};

  stageH(0, 0); stageH(0, 1); stageH(0, 2); stageH(0, 3);
  stageH(1, 0);
  WAITVM2;
  BARRIER;

  for (int p = 0; p < NP; ++p) {
    const int todd = 2 * p + 1, t2 = 2 * p + 2, t3 = 2 * p + 3;
    const bool last = (p == NP - 1);
    bf16x8 va[4][2], vb0[2][2], vb1[2][2];

    LDA4(va, 0, 0); LDB2(vb0, 0, 0);
    stageH(todd, 1);
    BARRIER; WAITLGKM0; PRIO1; MFQ(0, 0, va, vb0); PRIO0; BARRIER;
    LDB2(vb1, 2, 0);
    stageH(todd, 2);
    BARRIER; WAITLGKM0; PRIO1; MFQ(0, 2, va, vb1); PRIO0; BARRIER;
    LDA4(va, 4, 0);
    stageH(todd, 3);
    BARRIER; WAITLGKM0; PRIO1; MFQ(4, 0, va, vb0); PRIO0; BARRIER;
    if (t2 < nkt) stageH(t2, 0);
    BARRIER; PRIO1; MFQ(4, 2, va, vb1); PRIO0;
    if (last) { WAITVM0; } else { WAITVM2; }
    BARRIER;

    LDA4(va, 0, 32768); LDB2(vb0, 0, 32768);
    if (t2 < nkt) stageH(t2, 1);
    BARRIER; WAITLGKM0; PRIO1; MFQ(0, 0, va, vb0); PRIO0; BARRIER;
    LDB2(vb1, 2, 32768);
    if (t2 < nkt) stageH(t2, 2);
    BARRIER; WAITLGKM0; PRIO1; MFQ(0, 2, va, vb1); PRIO0; BARRIER;
    LDA4(va, 4, 32768);
    if (t2 < nkt) stageH(t2, 3);
    BARRIER; WAITLGKM0; PRIO1; MFQ(4, 0, va, vb0); PRIO0; BARRIER;
    if (t3 < nkt) stageH(t3, 0);
    BARRIER; PRIO1; MFQ(4, 2, va, vb1); PRIO0;
    if (!last) { WAITVM2; }
    BARRIER;
  }

  const int r0 = bm * 256 + wm * 128;
  const int c0 = bn * 256 + wn * 64;
  if (FUSE) {
    float bv[4], wv[4];
#pragma unroll
    for (int g = 0; g < 4; ++g) {
      const int col = c0 + g * 16 + fr;
      bv[g] = bias[col];
      wv[g] = w2[col];
    }
#pragma unroll
    for (int f = 0; f < 8; ++f) {
#pragma unroll
      for (int rr = 0; rr < 4; ++rr) {
        float s = 0.f;
#pragma unroll
        for (int g = 0; g < 4; ++g)
          s += fmaxf(acc[f][g][rr] + bv[g], 0.f) * wv[g];
#pragma unroll
        for (int off = 8; off >= 1; off >>= 1) s += __shfl_xor(s, off, 64);
        if (fr == 0)
          atomicAdd(&dotacc[r0 + f * 16 + fq * 4 + rr], s);
      }
    }
  } else {
#pragma unroll
    for (int g = 0; g < 4; ++g) {
      const int col = c0 + g * 16 + fr;
      const float bvv = bias[col];
#pragma unroll
      for (int f = 0; f < 8; ++f)
#pragma unroll
        for (int rr = 0; rr < 4; ++rr) {
          const int row = r0 + f * 16 + fq * 4 + rr;
          C[(size_t)row * N + col] = f2bf(fmaxf(acc[f][g][rr] + bvv, 0.f));
        }
    }
  }
}

// ---------------- fused embedding gather + interaction (R4 best config) ------
__global__ __launch_bounds__(256) void interact(const float* __restrict__ emb,
                                                const int* __restrict__ lsi,
                                                const u16* __restrict__ x3,
                                                u16* __restrict__ R) {
  __shared__ u16 lds[4 * 32 * 128];  // 32 KiB
  const int tid = threadIdx.x;
  const int b0 = blockIdx.x * 4;

  // zero rows 27..31 of each sample
  {
    u32* lz = (u32*)lds;
#pragma unroll
    for (int z = 0; z < 5; ++z) {
      int i = z * 256 + tid;           // 0..1279
      int s = i / 320, o = i - s * 320;
      lz[s * 2048 + 1728 + o] = 0u;
    }
  }
  // x3 -> row 0 (row&7==0: linear)
  if (tid < 64) {
    int s = tid >> 4, l = tid & 15;
    *(bf16x8*)&lds[(s * 32) * 128 + l * 8] =
        *(const bf16x8*)&x3[(size_t)(b0 + s) * 128 + l * 8];
  }
  // emb rows: 104 items, 32 lanes per item, 13 passes
  {
    const int lane32 = tid & 31;
    const int item0 = tid >> 5;        // 0..7
#pragma unroll
    for (int p = 0; p < 13; ++p) {
      int w = p * 8 + item0;           // 0..103
      int s = w / 26, t = w - s * 26;
      int idx = lsi[t * 32768 + b0 + s];
      const float* er =
          emb + ((size_t)t * 100000 + (size_t)idx) * 128 + lane32 * 4;
      f32x4 u = *(const f32x4*)er;
      u16x4 q;
      q[0] = f2bf(u[0]); q[1] = f2bf(u[1]); q[2] = f2bf(u[2]); q[3] = f2bf(u[3]);
      int r = t + 1;
      int chunk = (lane32 >> 1) ^ (r & 7);
      *(u16x4*)&lds[(s * 32 + r) * 128 + chunk * 8 + (lane32 & 1) * 4] = q;
    }
  }
  __syncthreads();

  const int wave = tid >> 6, lane = tid & 63;
  const int fr = lane & 15, fq = lane >> 4;
  const u16* ls = &lds[wave * 4096];
  u16* Rb = R + (size_t)(b0 + wave) * 512;

  *(u32*)&Rb[lane * 2] = *(const u32*)&ls[lane * 2];
  if (lane < 33) Rb[479 + lane] = 0;

  bf16x8 tf[2][4];
#pragma unroll
  for (int mi = 0; mi < 2; ++mi) {
    const int r = mi * 16 + fr;
#pragma unroll
    for (int ks = 0; ks < 4; ++ks) {
      const int chunk = (ks * 4 + fq) ^ (r & 7);
      tf[mi][ks] = *(const bf16x8*)&ls[r * 128 + chunk * 8];
    }
  }

  f32x4 acc[2][2] = {};
#pragma unroll
  for (int ks = 0; ks < 4; ++ks)
#pragma unroll
    for (int mi = 0; mi < 2; ++mi)
#pragma unroll
      for (int ni = 0; ni < 2; ++ni)
        acc[mi][ni] = __builtin_amdgcn_mfma_f32_16x16x32_bf16(
            tf[mi][ks], tf[ni][ks], acc[mi][ni], 0, 0, 0);

#pragma unroll
  for (int mi = 0; mi < 2; ++mi)
#pragma unroll
    for (int ni = 0; ni < 2; ++ni)
#pragma unroll
      for (int rr = 0; rr < 4; ++rr) {
        const int i = mi * 16 + fq * 4 + rr;
        const int j = ni * 16 + fr;
        if (i < 27 && j < i)
          Rb[128 + (i * (i - 1)) / 2 + j] = f2bf(acc[mi][ni][rr]);
      }
}

// ---------------- sigmoid ----------------
__global__ __launch_bounds__(256) void sig_k(const float* __restrict__ accv,
                                             const float* __restrict__ b2,
                                             float* __restrict__ out, int n) {
  int i = blockIdx.x * 256 + threadIdx.x;
  if (i < n) out[i] = 1.f / (1.f + expf(-(accv[i] + b2[0])));
}

// ---------------- launch ----------------
extern "C" void kernel_launch(void* const* d_in, const int* in_sizes, int n_in,
                              void* d_out, int out_size, void* d_ws,
                              size_t ws_size, hipStream_t stream) {
  const float* dense = (const float*)d_in[0];
  const int*   lsi   = (const int*)d_in[1];
  const float* emb = (const float*)d_in[3];
  const float* bw0 = (const float*)d_in[4];
  const float* bb0 = (const float*)d_in[5];
  const float* bw1 = (const float*)d_in[6];
  const float* bb1 = (const float*)d_in[7];
  const float* bw2 = (const float*)d_in[8];
  const float* bb2 = (const float*)d_in[9];
  const float* tw0 = (const float*)d_in[10];
  const float* tb0 = (const float*)d_in[11];
  const float* tw1 = (const float*)d_in[12];
  const float* tb1 = (const float*)d_in[13];
  const float* tw2 = (const float*)d_in[14];
  const float* tb2 = (const float*)d_in[15];

  char* ws = (char*)d_ws;
  u16* W1B  = (u16*)ws; ws += (size_t)256 * 512 * 2;
  u16* W2B  = (u16*)ws; ws += (size_t)128 * 256 * 2;
  u16* TW0B = (u16*)ws; ws += (size_t)1024 * 512 * 2;
  u16* TW1B = (u16*)ws; ws += (size_t)1024 * 1024 * 2;
  float* DOT = (float*)ws; ws += (size_t)32768 * 4;
  float* W0T = (float*)ws; ws += (size_t)13 * 512 * 4;
  u16* X3   = (u16*)ws; ws += (size_t)32768 * 128 * 2;
  u16* SA   = (u16*)ws; ws += (size_t)32768 * 1024 * 2;  // x1 -> R
  u16* SB   = (u16*)ws; ws += (size_t)32768 * 1024 * 2;  // x2 -> z1

  prep<<<(PREP_TOTAL + 255) / 256, 256, 0, stream>>>(
      bw0, bw1, bw2, tw0, tw1, W0T, W1B, W2B, TW0B, TW1B, DOT);

  bot0<<<2048, 256, 0, stream>>>(dense, W0T, bb0, SA);                        // x1
  gemm_bt_relu<<<512, 256, 0, stream>>>(SA, W1B, bb1, SB, 32768, 256, 512);   // x2
  gemm_bt_relu<<<256, 256, 0, stream>>>(SB, W2B, bb2, X3, 32768, 128, 256);   // x3
  interact<<<8192, 256, 0, stream>>>(emb, lsi, X3, SA);                       // R
  gemm256<0><<<512, 512, 0, stream>>>(SA, TW0B, tb0, SB, nullptr, nullptr,
                                      1024, 512);                             // z1
  gemm256<1><<<512, 512, 0, stream>>>(SB, TW1B, tb1, nullptr, tw2, DOT,
                                      1024, 1024);                            // z2.w2
  sig_k<<<128, 256, 0, stream>>>(DOT, tb2, (float*)d_out, 32768);
}